// Round 14
// baseline (207.449 us; speedup 1.0000x reference)
//
#include <hip/hip_runtime.h>
#include <hip/hip_bf16.h>

#define S_LEN 4096
#define DIM   1024
#define NH    16
#define HD    64

typedef unsigned short u16;
typedef short  bf16x8 __attribute__((ext_vector_type(8)));
typedef float  f32x4  __attribute__((ext_vector_type(4)));

__device__ __forceinline__ u16 f2bf(float f){
  union { float f; unsigned u; } x; x.f = f;
  unsigned u = x.u;
  return (u16)((u + 0x7FFFu + ((u >> 16) & 1u)) >> 16);
}
__device__ __forceinline__ unsigned pk2(float a, float b){
  union { __hip_bfloat162 h; unsigned u; } x;
  x.h = __float22bfloat162_rn(float2{a, b});
  return x.u;
}
// async global->LDS, 16B per lane (dest must be wave-uniform base + lane*16)
__device__ __forceinline__ void ld2lds16(const u16* g, u16* l){
  __builtin_amdgcn_global_load_lds((const __attribute__((address_space(1))) void*)g,
                                   (__attribute__((address_space(3))) void*)l, 16, 0, 0);
}

// Q pre-scale: 1/sqrt(64) * log2(e)  (softmax in exp2 domain; v_exp_f32 = 2^x)
#define QSCALE 0.1803368801111204f

__global__ __launch_bounds__(256) void fill_sentinel(float* __restrict__ out, int n){
  int i = blockIdx.x * 256 + threadIdx.x;
  if (i < n) out[i] = 77.0f;
}

// ---------------- fused prep: X fp32->bf16 (blocks 0..2047) + W transpose (2048..2815) ----------------
__global__ __launch_bounds__(256) void prep_fused(
    const float* __restrict__ X, u16* __restrict__ Xb,
    const float* __restrict__ W0, const float* __restrict__ W1, const float* __restrict__ W2,
    u16* __restrict__ Wt)
{
  __shared__ __align__(16) u16 tile[64*72];
  int b = blockIdx.x;
  int t = threadIdx.x;
  if (b < 2048){
    size_t i = ((size_t)b * 256 + t) * 8;
    float4 v0 = *(const float4*)(X + i);
    float4 v1 = *(const float4*)(X + i + 4);
    uint4 w;
    w.x = pk2(v0.x, v0.y); w.y = pk2(v0.z, v0.w);
    w.z = pk2(v1.x, v1.y); w.w = pk2(v1.z, v1.w);
    *(uint4*)(Xb + i) = w;
    return;
  }
  int tid = b - 2048;                 // 0..767
  int z   = tid >> 8;
  int rem = tid & 255;
  int k0  = (rem & 15) * 64, n0 = (rem >> 4) * 64;
  const float* W = z==0 ? W0 : z==1 ? W1 : W2;
  u16* T = Wt + (size_t)z * DIM * DIM;
  #pragma unroll
  for (int i = 0; i < 4; ++i){
    int idx = t + i*256;
    int row = idx >> 4, col4 = (idx & 15) * 4;
    float4 v = *(const float4*)(W + (size_t)(k0+row)*DIM + n0 + col4);
    tile[(col4+0)*72 + row] = f2bf(v.x);
    tile[(col4+1)*72 + row] = f2bf(v.y);
    tile[(col4+2)*72 + row] = f2bf(v.z);
    tile[(col4+3)*72 + row] = f2bf(v.w);
  }
  __syncthreads();
  #pragma unroll
  for (int i = 0; i < 2; ++i){
    int idx = t + i*256;
    int n = idx >> 3, k16 = (idx & 7) * 8;
    *(int4*)(T + (size_t)(n0+n)*DIM + k0 + k16) = *(const int4*)(tile + n*72 + k16);
  }
}

// ---------------- shared epilogue: C-frags -> Q / Kf / Vf ----------------
// Vf key-slot mapping (R4): slot (c2, q_slot, jj) holds phys key
//   s = 16*(2*c2 + (jj>>2)) + 4*q_slot + (jj&3)
// chosen so that attn's PV B-operand is a pure register concat of the QK
// C-frags after exp (zero cross-lane traffic, no LDS P roundtrip).
__device__ __forceinline__ void qkv_epilogue(
    int z, int m0, int n0, int wm, int wn, int quad, int l15,
    const f32x4 acc[4][4], const float* bias,
    u16* __restrict__ qb, u16* __restrict__ kf_out, u16* __restrict__ vf_out)
{
  #pragma unroll
  for (int nt=0; nt<4; ++nt){
    int n = n0 + wn + nt*16 + l15;
    float bv = bias[n];
    int h = n >> 6, d = n & 63;
    #pragma unroll
    for (int mt=0; mt<4; ++mt){
      int mb = m0 + wm + mt*16 + quad*4;   // C/D: row=quad*4+reg, col=l15
      f32x4 c = acc[mt][nt];
      if (z == 0){
        #pragma unroll
        for (int r=0; r<4; ++r)
          qb[(size_t)(mb + r)*DIM + n] = f2bf((c[r] + bv) * QSCALE);
      } else if (z == 1){
        int half = d >> 5, quadk = (d >> 3) & 3, j = d & 7;
        #pragma unroll
        for (int r=0; r<4; ++r){
          int s = mb + r;
          size_t idx = ((((size_t)h*256 + (s >> 4))*2 + half)*64 + quadk*16 + (s & 15))*8 + j;
          kf_out[idx] = f2bf(c[r] + bv);
        }
      } else {
        // keys mb..mb+3: kn,q_slot,c2 constant across r; jj = jj0 + r
        int kt64 = mb >> 6;
        int kn   = (mb >> 4) & 3;
        int qsl  = (mb >> 2) & 3;
        int h2   = kn >> 1;
        int jj0  = (kn & 1) * 4;
        int dt = d >> 4, dl = d & 15;
        size_t base = (((((size_t)h*64 + kt64)*4 + dt)*2 + h2)*64 + qsl*16 + dl)*8 + jj0;
        ushort4 p;
        p.x = f2bf(c[0]+bv); p.y = f2bf(c[1]+bv);
        p.z = f2bf(c[2]+bv); p.w = f2bf(c[3]+bv);
        *(ushort4*)(vf_out + base) = p;
      }
    }
  }
}

// ---------------- fast QKV GEMM: BK=32, double-buffered LDS (T3 minimum 2-phase) ----------------
// R14: the single-buffered loop issued loads and drained them at a barrier in the
// SAME iteration -> zero prefetch distance; every kt paid full L2 latency. Now:
// stage(kt+1) issues BEFORE compute(kt); the one barrier per kt drains loads that
// had a full compute phase (~400+cy) in flight. 2x16KB buffers per matrix (32KB).
// R12's verified swizzle (linear gload_lds dest + pre-permuted GLOBAL chunk,
// read chunk quad^((l15>>1)&3)) and XCD-locality grid kept. MFMA order per kt
// unchanged -> bit-identical numerics.
__global__ __launch_bounds__(256) void qkv_gemm_fast(
    const u16* __restrict__ Xbf, const u16* __restrict__ Wt,
    const float* __restrict__ b0, const float* __restrict__ b1, const float* __restrict__ b2,
    u16* __restrict__ qb, u16* __restrict__ kf_out, u16* __restrict__ vf_out)
{
  int fid = blockIdx.x;                 // 0..767
  int z   = fid >> 8;                   // 0..2
  int r   = fid & 255;
  int m0  = (((r & 7) << 2) + ((r >> 3) & 3)) * 128;  // XCD r&7 owns m-tiles [xcd*4, xcd*4+4)
  int n0  = (r >> 5) * 128;                            // 0..7

  const u16* Wz = Wt + (size_t)z * DIM * DIM;
  const float* bias = z==0 ? b0 : z==1 ? b1 : b2;

  // [buf][128 rows][32 u16]  -> 2 x 8 KB per matrix
  __shared__ __align__(16) u16 As[2*128*32];
  __shared__ __align__(16) u16 Bs[2*128*32];

  int t = threadIdx.x, wave = t >> 6, lane = t & 63, quad = lane >> 4, l15 = lane & 15;
  int wm = (wave >> 1) * 64, wn = (wave & 1) * 64;

  f32x4 acc[4][4];
  #pragma unroll
  for (int i=0;i<4;++i)
    #pragma unroll
    for (int j=0;j<4;++j) acc[i][j] = (f32x4){0.f,0.f,0.f,0.f};

  int srow = wave*32 + (lane >> 2);
  // global source chunk (inverse swizzle): c = (lane&3) ^ ((srow>>1)&3) ; (srow>>1)&3 == (lane>>3)&3
  int skc_g = (((lane & 3) ^ ((lane >> 3) & 3))) * 8;
  int skc_l = (lane & 3) * 8;           // linear LDS dest chunk
  const u16* gA0 = Xbf + (size_t)(m0 + srow)*DIM + skc_g;
  const u16* gA1 = gA0 + (size_t)16*DIM;
  const u16* gB0 = Wz  + (size_t)(n0 + srow)*DIM + skc_g;
  const u16* gB1 = gB0 + (size_t)16*DIM;
  u16* lA0 = As + srow*32 + skc_l;
  u16* lA1 = lA0 + 16*32;
  u16* lB0 = Bs + srow*32 + skc_l;
  u16* lB1 = lB0 + 16*32;

  // swizzled read offset: chunk q of row r lives at chunk q^((r>>1)&3)
  int swz = (quad ^ ((l15 >> 1) & 3)) * 8;

#define GSTAGE(P, KO)                                                            \
  do {                                                                           \
    ld2lds16(gA0 + (KO), lA0 + (P)*4096);                                        \
    ld2lds16(gA1 + (KO), lA1 + (P)*4096);                                        \
    ld2lds16(gB0 + (KO), lB0 + (P)*4096);                                        \
    ld2lds16(gB1 + (KO), lB1 + (P)*4096);                                        \
  } while(0)

#define GCOMPUTE(P)                                                              \
  do {                                                                           \
    bf16x8 af[4], bfr[4];                                                        \
    _Pragma("unroll")                                                            \
    for (int mt=0; mt<4; ++mt) af[mt]  = *(const bf16x8*)(As + (P)*4096 + (wm + mt*16 + l15)*32 + swz); \
    _Pragma("unroll")                                                            \
    for (int nt=0; nt<4; ++nt) bfr[nt] = *(const bf16x8*)(Bs + (P)*4096 + (wn + nt*16 + l15)*32 + swz); \
    _Pragma("unroll")                                                            \
    for (int mt=0; mt<4; ++mt)                                                   \
      _Pragma("unroll")                                                          \
      for (int nt=0; nt<4; ++nt)                                                 \
        acc[mt][nt] = __builtin_amdgcn_mfma_f32_16x16x32_bf16(af[mt], bfr[nt], acc[mt][nt], 0, 0, 0); \
  } while(0)

  GSTAGE(0, 0);
  __syncthreads();                      // tile 0 ready

  for (int kt = 0; kt < 32; kt += 2){
    // stage kt+1 into buf1 (issued BEFORE compute -> full phase of latency cover)
    GSTAGE(1, (kt+1)*32);
    GCOMPUTE(0);
    __syncthreads();                    // drains stage(kt+1); buf0 free
    if (kt + 2 < 32) GSTAGE(0, (kt+2)*32);
    GCOMPUTE(1);
    __syncthreads();                    // drains stage(kt+2); buf1 free
  }

#undef GSTAGE
#undef GCOMPUTE

  qkv_epilogue(z, m0, n0, wm, wn, quad, l15, acc, bias, qb, kf_out, vf_out);
}

// ---------------- legacy QKV GEMM (fp32 in; used when ws < 38 MB) ----------------
__global__ __launch_bounds__(256) void qkv_gemm_legacy(
    const float* __restrict__ X,
    const float* __restrict__ Wq, const float* __restrict__ Wk, const float* __restrict__ Wv,
    const float* __restrict__ b0, const float* __restrict__ b1, const float* __restrict__ b2,
    u16* __restrict__ qb, u16* __restrict__ kf_out, u16* __restrict__ vf_out)
{
  int z = blockIdx.z;
  const float* W    = z==0 ? Wq : z==1 ? Wk : Wv;
  const float* bias = z==0 ? b0 : z==1 ? b1 : b2;

  __shared__ __align__(16) u16 As[128*40];
  __shared__ __align__(16) u16 Bs[128*40];

  int m0 = blockIdx.x * 128, n0 = blockIdx.y * 128;
  int t = threadIdx.x, wave = t >> 6, lane = t & 63, quad = lane >> 4, l15 = lane & 15;
  int wm = (wave >> 1) * 64, wn = (wave & 1) * 64;

  f32x4 acc[4][4];
  #pragma unroll
  for (int i=0;i<4;++i)
    #pragma unroll
    for (int j=0;j<4;++j) acc[i][j] = (f32x4){0.f,0.f,0.f,0.f};

  int sr = t >> 2, sc = (t & 3) * 8;
  const float* gA0 = X + (size_t)(m0 + sr) * DIM + sc;
  const float* gA1 = X + (size_t)(m0 + 64 + sr) * DIM + sc;
  int br = t >> 3, bc = (t & 7) * 16;
  const float* gW = W + (size_t)br * DIM + n0 + bc;

  for (int kt = 0; kt < 32; ++kt){
    int ko = kt * 32;
    float4 a00 = *(const float4*)(gA0 + ko);
    float4 a01 = *(const float4*)(gA0 + ko + 4);
    float4 a10 = *(const float4*)(gA1 + ko);
    float4 a11 = *(const float4*)(gA1 + ko + 4);
    float4 w0  = *(const float4*)(gW + (size_t)ko*DIM);
    float4 w1  = *(const float4*)(gW + (size_t)ko*DIM + 4);
    float4 w2  = *(const float4*)(gW + (size_t)ko*DIM + 8);
    float4 w3  = *(const float4*)(gW + (size_t)ko*DIM + 12);
    int4 pa0, pa1;
    pa0.x = pk2(a00.x,a00.y); pa0.y = pk2(a00.z,a00.w);
    pa0.z = pk2(a01.x,a01.y); pa0.w = pk2(a01.z,a01.w);
    pa1.x = pk2(a10.x,a10.y); pa1.y = pk2(a10.z,a10.w);
    pa1.z = pk2(a11.x,a11.y); pa1.w = pk2(a11.z,a11.w);
    u16 wb[16];
    wb[0]=f2bf(w0.x); wb[1]=f2bf(w0.y); wb[2]=f2bf(w0.z); wb[3]=f2bf(w0.w);
    wb[4]=f2bf(w1.x); wb[5]=f2bf(w1.y); wb[6]=f2bf(w1.z); wb[7]=f2bf(w1.w);
    wb[8]=f2bf(w2.x); wb[9]=f2bf(w2.y); wb[10]=f2bf(w2.z); wb[11]=f2bf(w2.w);
    wb[12]=f2bf(w3.x); wb[13]=f2bf(w3.y); wb[14]=f2bf(w3.z); wb[15]=f2bf(w3.w);
    __syncthreads();
    *(int4*)(As + sr*40 + sc)      = pa0;
    *(int4*)(As + (64+sr)*40 + sc) = pa1;
    #pragma unroll
    for (int j=0;j<16;++j) Bs[(bc+j)*40 + br] = wb[j];
    __syncthreads();
    bf16x8 af[4], bfr[4];
    #pragma unroll
    for (int mt=0; mt<4; ++mt) af[mt]  = *(const bf16x8*)(As + (wm + mt*16 + l15)*40 + quad*8);
    #pragma unroll
    for (int nt=0; nt<4; ++nt) bfr[nt] = *(const bf16x8*)(Bs + (wn + nt*16 + l15)*40 + quad*8);
    #pragma unroll
    for (int mt=0; mt<4; ++mt)
      #pragma unroll
      for (int nt=0; nt<4; ++nt)
        acc[mt][nt] = __builtin_amdgcn_mfma_f32_16x16x32_bf16(af[mt], bfr[nt], acc[mt][nt], 0, 0, 0);
  }
  qkv_epilogue(z, m0, n0, wm, wn, quad, l15, acc, bias, qb, kf_out, vf_out);
}

// ---------------- flash attention: deferred-PV role split (unchanged from R11) ----------------
__global__ __launch_bounds__(256, 2) void attn(
    const u16* __restrict__ Qb, const u16* __restrict__ Kf,
    const u16* __restrict__ Vf, float* __restrict__ out)
{
  int fid = blockIdx.x;                 // 0..511
  int xcd  = fid & 7;                   // XCD assignment (id % 8)
  int hpar = (fid >> 3) & 1;
  int qb   = fid >> 4;                  // 0..31
  int h    = xcd*2 + hpar;              // heads {2x, 2x+1} pinned to XCD x

  int t = threadIdx.x, wave = t >> 6, lane = t & 63, quad = lane >> 4, l15 = lane & 15;
  int q0 = qb * 128 + wave * 32;
  int dg = (wave ^ (fid >> 8)) & 1;     // 0 = natural, 1 = deferred-PV

  __shared__ __align__(16) u16 Ks0[4096], Ks1[4096], Vs0[4096], Vs1[4096];

  const u16* Kfh = Kf + (size_t)h * 262144;
  const u16* Vfh = Vf + (size_t)h * 262144;

  bf16x8 qf[2][2];
  #pragma unroll
  for (int qs=0; qs<2; ++qs){
    const u16* Qp = Qb + (size_t)(q0 + qs*16 + l15)*DIM + h*HD;
    qf[qs][0] = *(const bf16x8*)(Qp + quad*8);
    qf[qs][1] = *(const bf16x8*)(Qp + 32 + quad*8);
  }

  f32x4 O[2][4];
  #pragma unroll
  for (int qs=0; qs<2; ++qs)
    #pragma unroll
    for (int dt=0; dt<4; ++dt) O[qs][dt] = (f32x4){0.f,0.f,0.f,0.f};
  float lsum[2] = {0.f, 0.f};

  typedef union { uint4 u; bf16x8 v; } pfu;

#define STAGE(KS, VS, T)                                                         \
  do {                                                                           \
    const u16* kg_ = Kfh + (size_t)(T)*4096 + t*8;                               \
    ld2lds16(kg_,        KS + t*8);                                              \
    ld2lds16(kg_ + 2048, KS + t*8 + 2048);                                       \
    const u16* vg_ = Vfh + (size_t)(T)*4096 + t*8;                               \
    ld2lds16(vg_,        VS + t*8);                                              \
    ld2lds16(vg_ + 2048, VS + t*8 + 2048);                                       \
  } while(0)

#define QK_EXP(KS, PF)                                                           \
  do {                                                                           \
    bf16x8 kfr[4][2];                                                            \
    _Pragma("unroll")                                                            \
    for (int kn=0; kn<4; ++kn)                                                   \
      _Pragma("unroll")                                                          \
      for (int hf=0; hf<2; ++hf)                                                 \
        kfr[kn][hf] = *(const bf16x8*)((KS) + (kn*2+hf)*512 + lane*8);           \
    f32x4 st[2][4];                                                              \
    __builtin_amdgcn_s_setprio(1);                                               \
    _Pragma("unroll")                                                            \
    for (int qs=0; qs<2; ++qs)                                                   \
      _Pragma("unroll")                                                          \
      for (int kn=0; kn<4; ++kn){                                                \
        f32x4 zz = (f32x4){0.f,0.f,0.f,0.f};                                     \
        zz = __builtin_amdgcn_mfma_f32_16x16x32_bf16(kfr[kn][0], qf[qs][0], zz, 0,0,0); \
        zz = __builtin_amdgcn_mfma_f32_16x16x32_bf16(kfr[kn][1], qf[qs][1], zz, 0,0,0); \
        st[qs][kn] = zz;                                                         \
      }                                                                          \
    __builtin_amdgcn_s_setprio(0);                                               \
    _Pragma("unroll")                                                            \
    for (int qs=0; qs<2; ++qs){                                                  \
      float ls = 0.f;                                                            \
      _Pragma("unroll")                                                          \
      for (int kn=0; kn<4; ++kn)                                                 \
        _Pragma("unroll")                                                        \
        for (int r=0; r<4; ++r){                                                 \
          float p = __builtin_amdgcn_exp2f(st[qs][kn][r]);                       \
          st[qs][kn][r] = p; ls += p;                                            \
        }                                                                        \
      lsum[qs] += ls;                                                            \
      PF[qs][0].u.x = pk2(st[qs][0][0], st[qs][0][1]);                           \
      PF[qs][0].u.y = pk2(st[qs][0][2], st[qs][0][3]);                           \
      PF[qs][0].u.z = pk2(st[qs][1][0], st[qs][1][1]);                           \
      PF[qs][0].u.w = pk2(st[qs][1][2], st[qs][1][3]);                           \
      PF[qs][1].u.x = pk2(st[qs][2][0], st[qs][2][1]);                           \
      PF[qs][1].u.y = pk2(st[qs][2][2], st[qs][2][3]);                           \
      PF[qs][1].u.z = pk2(st[qs][3][0], st[qs][3][1]);                           \
      PF[qs][1].u.w = pk2(st[qs][3][2], st[qs][3][3]);                           \
    }                                                                            \
  } while(0)

#define LOADV(VFR, VS)                                                           \
  do {                                                                           \
    _Pragma("unroll")                                                            \
    for (int dt=0; dt<4; ++dt)                                                   \
      _Pragma("unroll")                                                          \
      for (int c2=0; c2<2; ++c2)                                                 \
        VFR[dt][c2] = *(const bf16x8*)((VS) + (dt*2+c2)*512 + lane*8);           \
  } while(0)

#define PV(PF, VFR)                                                              \
  do {                                                                           \
    __builtin_amdgcn_s_setprio(1);                                               \
    _Pragma("unroll")                                                            \
    for (int qs=0; qs<2; ++qs)                                                   \
      _Pragma("unroll")                                                          \
      for (int dt=0; dt<4; ++dt){                                                \
        f32x4 o = O[qs][dt];                                                     \
        o = __builtin_amdgcn_mfma_f32_16x16x32_bf16(VFR[dt][0], PF[qs][0].v, o, 0,0,0); \
        o = __builtin_amdgcn_mfma_f32_16x16x32_bf16(VFR[dt][1], PF[qs][1].v, o, 0,0,0); \
        O[qs][dt] = o;                                                           \
      }                                                                          \
    __builtin_amdgcn_s_setprio(0);                                               \
  } while(0)

#define COMPUTE(KS, VS, FIRST)                                                   \
  do {                                                                           \
    if (!dg){                                                                    \
      pfu pfN[2][2]; bf16x8 vfrN[4][2];                                          \
      QK_EXP(KS, pfN);                                                           \
      LOADV(vfrN, VS);                                                           \
      PV(pfN, vfrN);                                                             \
    } else {                                                                     \
      if (!(FIRST)) PV(pfC, vfrC);                                               \
      QK_EXP(KS, pfC);                                                           \
      LOADV(vfrC, VS);                                                           \
    }                                                                            \
  } while(0)

  pfu pfC[2][2];
  bf16x8 vfrC[4][2];

  STAGE(Ks0, Vs0, 0);
  __syncthreads();
  STAGE(Ks1, Vs1, 1);
  COMPUTE(Ks0, Vs0, 1);
  __syncthreads();

  for (int kt = 1; kt < 63; kt += 2){
    STAGE(Ks0, Vs0, kt+1);
    COMPUTE(Ks1, Vs1, 0);
    __syncthreads();
    STAGE(Ks1, Vs1, kt+2);
    COMPUTE(Ks0, Vs0, 0);
    __syncthreads();
  }
  COMPUTE(Ks1, Vs1, 0);
  if (dg) PV(pfC, vfrC);

#undef STAGE
#undef QK_EXP
#undef LOADV
#undef PV
#undef COMPUTE

  #pragma unroll
  for (int qs=0; qs<2; ++qs){
    float l = lsum[qs];
    l += __shfl_xor(l, 16, 64);
    l += __shfl_xor(l, 32, 64);
    float inv = 1.0f / l;
    int query = q0 + qs*16 + l15;
    #pragma unroll
    for (int dt=0; dt<4; ++dt){
      float4 v;
      v.x = O[qs][dt][0]*inv; v.y = O[qs][dt][1]*inv;
      v.z = O[qs][dt][2]*inv; v.w = O[qs][dt][3]*inv;
      *(float4*)(out + (size_t)query*DIM + h*HD + dt*16 + quad*4) = v;
    }
  }
}

extern "C" void kernel_launch(void* const* d_in, const int* in_sizes, int n_in,
                              void* d_out, int out_size, void* d_ws, size_t ws_size,
                              hipStream_t stream)
{
  const float* X  = (const float*)d_in[0];
  const float* Wq = (const float*)d_in[1];
  const float* bq = (const float*)d_in[2];
  const float* Wk = (const float*)d_in[3];
  const float* bk = (const float*)d_in[4];
  const float* Wv = (const float*)d_in[5];
  const float* bv = (const float*)d_in[6];
  float* out = (float*)d_out;
  u16*   ws  = (u16*)d_ws;

  const size_t SD = (size_t)S_LEN * DIM;
  const size_t need_fast = (4*SD + 3*(size_t)DIM*DIM) * sizeof(u16);  // ~38 MB
  const size_t need_min  = (size_t)24 * 1024 * 1024;

  if (ws_size >= need_fast){
    u16* xbf = ws;
    u16* wt  = xbf + SD;
    u16* qb  = wt + 3*(size_t)DIM*DIM;
    u16* kf  = qb + SD;
    u16* vf  = kf + SD;
    prep_fused   <<<dim3(2048 + 768), 256, 0, stream>>>(X, xbf, Wq, Wk, Wv, wt);
    qkv_gemm_fast<<<dim3(768), 256, 0, stream>>>(xbf, wt, bq, bk, bv, qb, kf, vf);
    attn         <<<dim3(512), 256, 0, stream>>>(qb, kf, vf, out);
  } else if (ws_size >= need_min){
    u16* qb = ws;
    u16* kf = qb + SD;
    u16* vf = kf + SD;
    qkv_gemm_legacy<<<dim3(32, 8, 3), 256, 0, stream>>>(X, Wq, Wk, Wv, bq, bk, bv, qb, kf, vf);
    attn           <<<dim3(512), 256, 0, stream>>>(qb, kf, vf, out);
  } else {
    fill_sentinel<<<(out_size + 255)/256, 256, 0, stream>>>(out, out_size);
  }
}

// Round 15
// 193.806 us; speedup vs baseline: 1.0704x; 1.0704x over previous
//
#include <hip/hip_runtime.h>
#include <hip/hip_bf16.h>

#define S_LEN 4096
#define DIM   1024
#define NH    16
#define HD    64

typedef unsigned short u16;
typedef short  bf16x8 __attribute__((ext_vector_type(8)));
typedef float  f32x4  __attribute__((ext_vector_type(4)));

__device__ __forceinline__ u16 f2bf(float f){
  union { float f; unsigned u; } x; x.f = f;
  unsigned u = x.u;
  return (u16)((u + 0x7FFFu + ((u >> 16) & 1u)) >> 16);
}
__device__ __forceinline__ unsigned pk2(float a, float b){
  union { __hip_bfloat162 h; unsigned u; } x;
  x.h = __float22bfloat162_rn(float2{a, b});
  return x.u;
}
// async global->LDS, 16B per lane (dest must be wave-uniform base + lane*16)
__device__ __forceinline__ void ld2lds16(const u16* g, u16* l){
  __builtin_amdgcn_global_load_lds((const __attribute__((address_space(1))) void*)g,
                                   (__attribute__((address_space(3))) void*)l, 16, 0, 0);
}

// Q pre-scale: 1/sqrt(64) * log2(e)  (softmax in exp2 domain; v_exp_f32 = 2^x)
#define QSCALE 0.1803368801111204f

__global__ __launch_bounds__(256) void fill_sentinel(float* __restrict__ out, int n){
  int i = blockIdx.x * 256 + threadIdx.x;
  if (i < n) out[i] = 77.0f;
}

// ---------------- fused prep: X fp32->bf16 (blocks 0..2047) + W transpose (2048..2815) ----------------
__global__ __launch_bounds__(256) void prep_fused(
    const float* __restrict__ X, u16* __restrict__ Xb,
    const float* __restrict__ W0, const float* __restrict__ W1, const float* __restrict__ W2,
    u16* __restrict__ Wt)
{
  __shared__ __align__(16) u16 tile[64*72];
  int b = blockIdx.x;
  int t = threadIdx.x;
  if (b < 2048){
    size_t i = ((size_t)b * 256 + t) * 8;
    float4 v0 = *(const float4*)(X + i);
    float4 v1 = *(const float4*)(X + i + 4);
    uint4 w;
    w.x = pk2(v0.x, v0.y); w.y = pk2(v0.z, v0.w);
    w.z = pk2(v1.x, v1.y); w.w = pk2(v1.z, v1.w);
    *(uint4*)(Xb + i) = w;
    return;
  }
  int tid = b - 2048;                 // 0..767
  int z   = tid >> 8;
  int rem = tid & 255;
  int k0  = (rem & 15) * 64, n0 = (rem >> 4) * 64;
  const float* W = z==0 ? W0 : z==1 ? W1 : W2;
  u16* T = Wt + (size_t)z * DIM * DIM;
  #pragma unroll
  for (int i = 0; i < 4; ++i){
    int idx = t + i*256;
    int row = idx >> 4, col4 = (idx & 15) * 4;
    float4 v = *(const float4*)(W + (size_t)(k0+row)*DIM + n0 + col4);
    tile[(col4+0)*72 + row] = f2bf(v.x);
    tile[(col4+1)*72 + row] = f2bf(v.y);
    tile[(col4+2)*72 + row] = f2bf(v.z);
    tile[(col4+3)*72 + row] = f2bf(v.w);
  }
  __syncthreads();
  #pragma unroll
  for (int i = 0; i < 2; ++i){
    int idx = t + i*256;
    int n = idx >> 3, k16 = (idx & 7) * 8;
    *(int4*)(T + (size_t)(n0+n)*DIM + k0 + k16) = *(const int4*)(tile + n*72 + k16);
  }
}

// ---------------- legacy epilogue (kept for qkv_gemm_legacy only) ----------------
__device__ __forceinline__ void qkv_epilogue(
    int z, int m0, int n0, int wm, int wn, int quad, int l15,
    const f32x4 acc[4][4], const float* bias,
    u16* __restrict__ qb, u16* __restrict__ kf_out, u16* __restrict__ vf_out)
{
  #pragma unroll
  for (int nt=0; nt<4; ++nt){
    int n = n0 + wn + nt*16 + l15;
    float bv = bias[n];
    int h = n >> 6, d = n & 63;
    #pragma unroll
    for (int mt=0; mt<4; ++mt){
      int mb = m0 + wm + mt*16 + quad*4;   // C/D: row=quad*4+reg, col=l15
      f32x4 c = acc[mt][nt];
      if (z == 0){
        #pragma unroll
        for (int r=0; r<4; ++r)
          qb[(size_t)(mb + r)*DIM + n] = f2bf((c[r] + bv) * QSCALE);
      } else if (z == 1){
        int half = d >> 5, quadk = (d >> 3) & 3, j = d & 7;
        #pragma unroll
        for (int r=0; r<4; ++r){
          int s = mb + r;
          size_t idx = ((((size_t)h*256 + (s >> 4))*2 + half)*64 + quadk*16 + (s & 15))*8 + j;
          kf_out[idx] = f2bf(c[r] + bv);
        }
      } else {
        int kt64 = mb >> 6;
        int kn   = (mb >> 4) & 3;
        int qsl  = (mb >> 2) & 3;
        int h2   = kn >> 1;
        int jj0  = (kn & 1) * 4;
        int dt = d >> 4, dl = d & 15;
        size_t base = (((((size_t)h*64 + kt64)*4 + dt)*2 + h2)*64 + qsl*16 + dl)*8 + jj0;
        ushort4 p;
        p.x = f2bf(c[0]+bv); p.y = f2bf(c[1]+bv);
        p.z = f2bf(c[2]+bv); p.w = f2bf(c[3]+bv);
        *(ushort4*)(vf_out + base) = p;
      }
    }
  }
}

// ---------------- fast QKV GEMM: dbuf loop + LDS-staged COALESCED epilogue ----------------
// R15: R12/R13/R14 proved the main loop is not the GEMM's cost. The epilogue was:
// z<=1 issued 64 scalar 2B scattered global stores per thread (~12.6M stores).
// Now: after the K-loop the 32KB As/Bs are dead; stage bf16 C into SMEM in the
// output-local layout (Q/K: [key][136-pad local-n]; V: native 4-chunk layout),
// one barrier, then 8x uint4 copy-out per thread -> every global store is 16B,
// wave-contiguous. Values bit-identical (same f2bf(c+bv), just routed via LDS).
__global__ __launch_bounds__(256) void qkv_gemm_fast(
    const u16* __restrict__ Xbf, const u16* __restrict__ Wt,
    const float* __restrict__ b0, const float* __restrict__ b1, const float* __restrict__ b2,
    u16* __restrict__ qb, u16* __restrict__ kf_out, u16* __restrict__ vf_out)
{
  int fid = blockIdx.x;                 // 0..767
  int z   = fid >> 8;                   // 0..2
  int r   = fid & 255;
  int m0  = (((r & 7) << 2) + ((r >> 3) & 3)) * 128;  // XCD r&7 owns m-tiles [xcd*4, xcd*4+4)
  int n0  = (r >> 5) * 128;                            // 0..7

  const u16* Wz = Wt + (size_t)z * DIM * DIM;
  const float* bias = z==0 ? b0 : z==1 ? b1 : b2;

  // 34816 B: main loop uses [0,32KB) as As/Bs; epilogue reuses all of it
  __shared__ __align__(16) u16 SMEM[128*136];
  u16* As = SMEM;            // 2*128*32 = 8192 u16
  u16* Bs = SMEM + 8192;     // 8192 u16

  int t = threadIdx.x, wave = t >> 6, lane = t & 63, quad = lane >> 4, l15 = lane & 15;
  int wm = (wave >> 1) * 64, wn = (wave & 1) * 64;

  f32x4 acc[4][4];
  #pragma unroll
  for (int i=0;i<4;++i)
    #pragma unroll
    for (int j=0;j<4;++j) acc[i][j] = (f32x4){0.f,0.f,0.f,0.f};

  int srow = wave*32 + (lane >> 2);
  int skc_g = (((lane & 3) ^ ((lane >> 3) & 3))) * 8;  // pre-swizzled global chunk
  int skc_l = (lane & 3) * 8;                          // linear LDS dest chunk
  const u16* gA0 = Xbf + (size_t)(m0 + srow)*DIM + skc_g;
  const u16* gA1 = gA0 + (size_t)16*DIM;
  const u16* gB0 = Wz  + (size_t)(n0 + srow)*DIM + skc_g;
  const u16* gB1 = gB0 + (size_t)16*DIM;
  u16* lA0 = As + srow*32 + skc_l;
  u16* lA1 = lA0 + 16*32;
  u16* lB0 = Bs + srow*32 + skc_l;
  u16* lB1 = lB0 + 16*32;

  int swz = (quad ^ ((l15 >> 1) & 3)) * 8;             // swizzled read chunk

#define GSTAGE(P, KO)                                                            \
  do {                                                                           \
    ld2lds16(gA0 + (KO), lA0 + (P)*4096);                                        \
    ld2lds16(gA1 + (KO), lA1 + (P)*4096);                                        \
    ld2lds16(gB0 + (KO), lB0 + (P)*4096);                                        \
    ld2lds16(gB1 + (KO), lB1 + (P)*4096);                                        \
  } while(0)

#define GCOMPUTE(P)                                                              \
  do {                                                                           \
    bf16x8 af[4], bfr[4];                                                        \
    _Pragma("unroll")                                                            \
    for (int mt=0; mt<4; ++mt) af[mt]  = *(const bf16x8*)(As + (P)*4096 + (wm + mt*16 + l15)*32 + swz); \
    _Pragma("unroll")                                                            \
    for (int nt=0; nt<4; ++nt) bfr[nt] = *(const bf16x8*)(Bs + (P)*4096 + (wn + nt*16 + l15)*32 + swz); \
    _Pragma("unroll")                                                            \
    for (int mt=0; mt<4; ++mt)                                                   \
      _Pragma("unroll")                                                          \
      for (int nt=0; nt<4; ++nt)                                                 \
        acc[mt][nt] = __builtin_amdgcn_mfma_f32_16x16x32_bf16(af[mt], bfr[nt], acc[mt][nt], 0, 0, 0); \
  } while(0)

  GSTAGE(0, 0);
  __syncthreads();

  for (int kt = 0; kt < 32; kt += 2){
    GSTAGE(1, (kt+1)*32);
    GCOMPUTE(0);
    __syncthreads();
    if (kt + 2 < 32) GSTAGE(0, (kt+2)*32);
    GCOMPUTE(1);
    __syncthreads();                    // after final iter: all As/Bs reads done -> SMEM reusable
  }

#undef GSTAGE
#undef GCOMPUTE

  // ---- stage C (bf16, bias applied) into SMEM in output-local layout ----
  #pragma unroll
  for (int nt=0; nt<4; ++nt){
    int nl = wn + nt*16 + l15;          // local n 0..127
    int n  = n0 + nl;
    float bv = bias[n];
    #pragma unroll
    for (int mt=0; mt<4; ++mt){
      int mbl = wm + mt*16 + quad*4;    // local key/row 0..127
      f32x4 c = acc[mt][nt];
      if (z == 0){
        #pragma unroll
        for (int rr=0; rr<4; ++rr)
          SMEM[(mbl+rr)*136 + nl] = f2bf((c[rr] + bv) * QSCALE);
      } else if (z == 1){
        #pragma unroll
        for (int rr=0; rr<4; ++rr)
          SMEM[(mbl+rr)*136 + nl] = f2bf(c[rr] + bv);
      } else {
        // V-local layout: ((((hh*2+k64l)*4 + dt)*2 + h2)*64 + qsl*16 + l15)*8 + jj0
        int k64l = (mbl >> 6) & 1;
        int kn   = (mbl >> 4) & 3;
        int qsl  = (mbl >> 2) & 3;
        int h2   = kn >> 1;
        int jj0  = (kn & 1) * 4;
        int hh   = wn >> 6;             // local head 0/1 (wave-uniform)
        int dt   = nt;                  // (local n & 63)>>4 == nt
        int addr = ((((hh*2 + k64l)*4 + dt)*2 + h2)*64 + qsl*16 + l15)*8 + jj0;
        ushort4 p;
        p.x = f2bf(c[0]+bv); p.y = f2bf(c[1]+bv);
        p.z = f2bf(c[2]+bv); p.w = f2bf(c[3]+bv);
        *(ushort4*)(SMEM + addr) = p;
      }
    }
  }
  __syncthreads();

  // ---- coalesced copy-out: 8 x 16B per thread ----
  if (z == 0){
    #pragma unroll
    for (int i=0; i<8; ++i){
      int u = t + i*256;                // 0..2047
      int row = u >> 4, cu = u & 15;
      *(uint4*)(qb + (size_t)(m0+row)*DIM + n0 + cu*8) =
          *(const uint4*)(SMEM + row*136 + cu*8);
    }
  } else if (z == 1){
    #pragma unroll
    for (int i=0; i<8; ++i){
      int u = t + i*256;
      int c  = u >> 6;                  // chunk 0..31 (1KB each)
      int w  = u & 63;
      int qk = w >> 4, sk = w & 15;
      int g  = c >> 2, hh = (c >> 1) & 1, half = c & 1;
      int hgl = (n0 >> 6) + hh;
      size_t dst = ((((size_t)hgl*256 + (m0>>4) + g)*2 + half)*64 + qk*16 + sk)*8;
      *(uint4*)(kf_out + dst) =
          *(const uint4*)(SMEM + (g*16+sk)*136 + hh*64 + half*32 + qk*8);
    }
  } else {
    #pragma unroll
    for (int i=0; i<8; ++i){
      int u = t + i*256;
      int chunk = u >> 9;               // 4 chunks of 8KB
      int w = u & 511;
      int hh = chunk >> 1, k64l = chunk & 1;
      int hgl = (n0 >> 6) + hh;
      size_t dst = ((size_t)hgl*64 + (m0>>6) + k64l)*4096 + (size_t)w*8;
      *(uint4*)(vf_out + dst) = *(const uint4*)(SMEM + chunk*4096 + w*8);
    }
  }
}

// ---------------- legacy QKV GEMM (fp32 in; used when ws < 38 MB) ----------------
__global__ __launch_bounds__(256) void qkv_gemm_legacy(
    const float* __restrict__ X,
    const float* __restrict__ Wq, const float* __restrict__ Wk, const float* __restrict__ Wv,
    const float* __restrict__ b0, const float* __restrict__ b1, const float* __restrict__ b2,
    u16* __restrict__ qb, u16* __restrict__ kf_out, u16* __restrict__ vf_out)
{
  int z = blockIdx.z;
  const float* W    = z==0 ? Wq : z==1 ? Wk : Wv;
  const float* bias = z==0 ? b0 : z==1 ? b1 : b2;

  __shared__ __align__(16) u16 As[128*40];
  __shared__ __align__(16) u16 Bs[128*40];

  int m0 = blockIdx.x * 128, n0 = blockIdx.y * 128;
  int t = threadIdx.x, wave = t >> 6, lane = t & 63, quad = lane >> 4, l15 = lane & 15;
  int wm = (wave >> 1) * 64, wn = (wave & 1) * 64;

  f32x4 acc[4][4];
  #pragma unroll
  for (int i=0;i<4;++i)
    #pragma unroll
    for (int j=0;j<4;++j) acc[i][j] = (f32x4){0.f,0.f,0.f,0.f};

  int sr = t >> 2, sc = (t & 3) * 8;
  const float* gA0 = X + (size_t)(m0 + sr) * DIM + sc;
  const float* gA1 = X + (size_t)(m0 + 64 + sr) * DIM + sc;
  int br = t >> 3, bc = (t & 7) * 16;
  const float* gW = W + (size_t)br * DIM + n0 + bc;

  for (int kt = 0; kt < 32; ++kt){
    int ko = kt * 32;
    float4 a00 = *(const float4*)(gA0 + ko);
    float4 a01 = *(const float4*)(gA0 + ko + 4);
    float4 a10 = *(const float4*)(gA1 + ko);
    float4 a11 = *(const float4*)(gA1 + ko + 4);
    float4 w0  = *(const float4*)(gW + (size_t)ko*DIM);
    float4 w1  = *(const float4*)(gW + (size_t)ko*DIM + 4);
    float4 w2  = *(const float4*)(gW + (size_t)ko*DIM + 8);
    float4 w3  = *(const float4*)(gW + (size_t)ko*DIM + 12);
    int4 pa0, pa1;
    pa0.x = pk2(a00.x,a00.y); pa0.y = pk2(a00.z,a00.w);
    pa0.z = pk2(a01.x,a01.y); pa0.w = pk2(a01.z,a01.w);
    pa1.x = pk2(a10.x,a10.y); pa1.y = pk2(a10.z,a10.w);
    pa1.z = pk2(a11.x,a11.y); pa1.w = pk2(a11.z,a11.w);
    u16 wb[16];
    wb[0]=f2bf(w0.x); wb[1]=f2bf(w0.y); wb[2]=f2bf(w0.z); wb[3]=f2bf(w0.w);
    wb[4]=f2bf(w1.x); wb[5]=f2bf(w1.y); wb[6]=f2bf(w1.z); wb[7]=f2bf(w1.w);
    wb[8]=f2bf(w2.x); wb[9]=f2bf(w2.y); wb[10]=f2bf(w2.z); wb[11]=f2bf(w2.w);
    wb[12]=f2bf(w3.x); wb[13]=f2bf(w3.y); wb[14]=f2bf(w3.z); wb[15]=f2bf(w3.w);
    __syncthreads();
    *(int4*)(As + sr*40 + sc)      = pa0;
    *(int4*)(As + (64+sr)*40 + sc) = pa1;
    #pragma unroll
    for (int j=0;j<16;++j) Bs[(bc+j)*40 + br] = wb[j];
    __syncthreads();
    bf16x8 af[4], bfr[4];
    #pragma unroll
    for (int mt=0; mt<4; ++mt) af[mt]  = *(const bf16x8*)(As + (wm + mt*16 + l15)*40 + quad*8);
    #pragma unroll
    for (int nt=0; nt<4; ++nt) bfr[nt] = *(const bf16x8*)(Bs + (wn + nt*16 + l15)*40 + quad*8);
    #pragma unroll
    for (int mt=0; mt<4; ++mt)
      #pragma unroll
      for (int nt=0; nt<4; ++nt)
        acc[mt][nt] = __builtin_amdgcn_mfma_f32_16x16x32_bf16(af[mt], bfr[nt], acc[mt][nt], 0, 0, 0);
  }
  qkv_epilogue(z, m0, n0, wm, wn, quad, l15, acc, bias, qb, kf_out, vf_out);
}

// ---------------- flash attention: deferred-PV role split (unchanged from R11) ----------------
__global__ __launch_bounds__(256, 2) void attn(
    const u16* __restrict__ Qb, const u16* __restrict__ Kf,
    const u16* __restrict__ Vf, float* __restrict__ out)
{
  int fid = blockIdx.x;                 // 0..511
  int xcd  = fid & 7;                   // XCD assignment (id % 8)
  int hpar = (fid >> 3) & 1;
  int qb   = fid >> 4;                  // 0..31
  int h    = xcd*2 + hpar;              // heads {2x, 2x+1} pinned to XCD x

  int t = threadIdx.x, wave = t >> 6, lane = t & 63, quad = lane >> 4, l15 = lane & 15;
  int q0 = qb * 128 + wave * 32;
  int dg = (wave ^ (fid >> 8)) & 1;     // 0 = natural, 1 = deferred-PV

  __shared__ __align__(16) u16 Ks0[4096], Ks1[4096], Vs0[4096], Vs1[4096];

  const u16* Kfh = Kf + (size_t)h * 262144;
  const u16* Vfh = Vf + (size_t)h * 262144;

  bf16x8 qf[2][2];
  #pragma unroll
  for (int qs=0; qs<2; ++qs){
    const u16* Qp = Qb + (size_t)(q0 + qs*16 + l15)*DIM + h*HD;
    qf[qs][0] = *(const bf16x8*)(Qp + quad*8);
    qf[qs][1] = *(const bf16x8*)(Qp + 32 + quad*8);
  }

  f32x4 O[2][4];
  #pragma unroll
  for (int qs=0; qs<2; ++qs)
    #pragma unroll
    for (int dt=0; dt<4; ++dt) O[qs][dt] = (f32x4){0.f,0.f,0.f,0.f};
  float lsum[2] = {0.f, 0.f};

  typedef union { uint4 u; bf16x8 v; } pfu;

#define STAGE(KS, VS, T)                                                         \
  do {                                                                           \
    const u16* kg_ = Kfh + (size_t)(T)*4096 + t*8;                               \
    ld2lds16(kg_,        KS + t*8);                                              \
    ld2lds16(kg_ + 2048, KS + t*8 + 2048);                                       \
    const u16* vg_ = Vfh + (size_t)(T)*4096 + t*8;                               \
    ld2lds16(vg_,        VS + t*8);                                              \
    ld2lds16(vg_ + 2048, VS + t*8 + 2048);                                       \
  } while(0)

#define QK_EXP(KS, PF)                                                           \
  do {                                                                           \
    bf16x8 kfr[4][2];                                                            \
    _Pragma("unroll")                                                            \
    for (int kn=0; kn<4; ++kn)                                                   \
      _Pragma("unroll")                                                          \
      for (int hf=0; hf<2; ++hf)                                                 \
        kfr[kn][hf] = *(const bf16x8*)((KS) + (kn*2+hf)*512 + lane*8);           \
    f32x4 st[2][4];                                                              \
    __builtin_amdgcn_s_setprio(1);                                               \
    _Pragma("unroll")                                                            \
    for (int qs=0; qs<2; ++qs)                                                   \
      _Pragma("unroll")                                                          \
      for (int kn=0; kn<4; ++kn){                                                \
        f32x4 zz = (f32x4){0.f,0.f,0.f,0.f};                                     \
        zz = __builtin_amdgcn_mfma_f32_16x16x32_bf16(kfr[kn][0], qf[qs][0], zz, 0,0,0); \
        zz = __builtin_amdgcn_mfma_f32_16x16x32_bf16(kfr[kn][1], qf[qs][1], zz, 0,0,0); \
        st[qs][kn] = zz;                                                         \
      }                                                                          \
    __builtin_amdgcn_s_setprio(0);                                               \
    _Pragma("unroll")                                                            \
    for (int qs=0; qs<2; ++qs){                                                  \
      float ls = 0.f;                                                            \
      _Pragma("unroll")                                                          \
      for (int kn=0; kn<4; ++kn)                                                 \
        _Pragma("unroll")                                                        \
        for (int r=0; r<4; ++r){                                                 \
          float p = __builtin_amdgcn_exp2f(st[qs][kn][r]);                       \
          st[qs][kn][r] = p; ls += p;                                            \
        }                                                                        \
      lsum[qs] += ls;                                                            \
      PF[qs][0].u.x = pk2(st[qs][0][0], st[qs][0][1]);                           \
      PF[qs][0].u.y = pk2(st[qs][0][2], st[qs][0][3]);                           \
      PF[qs][0].u.z = pk2(st[qs][1][0], st[qs][1][1]);                           \
      PF[qs][0].u.w = pk2(st[qs][1][2], st[qs][1][3]);                           \
      PF[qs][1].u.x = pk2(st[qs][2][0], st[qs][2][1]);                           \
      PF[qs][1].u.y = pk2(st[qs][2][2], st[qs][2][3]);                           \
      PF[qs][1].u.z = pk2(st[qs][3][0], st[qs][3][1]);                           \
      PF[qs][1].u.w = pk2(st[qs][3][2], st[qs][3][3]);                           \
    }                                                                            \
  } while(0)

#define LOADV(VFR, VS)                                                           \
  do {                                                                           \
    _Pragma("unroll")                                                            \
    for (int dt=0; dt<4; ++dt)                                                   \
      _Pragma("unroll")                                                          \
      for (int c2=0; c2<2; ++c2)                                                 \
        VFR[dt][c2] = *(const bf16x8*)((VS) + (dt*2+c2)*512 + lane*8);           \
  } while(0)

#define PV(PF, VFR)                                                              \
  do {                                                                           \
    __builtin_amdgcn_s_setprio(1);                                               \
    _Pragma("unroll")                                                            \
    for (int qs=0; qs<2; ++qs)                                                   \
      _Pragma("unroll")                                                          \
      for (int dt=0; dt<4; ++dt){                                                \
        f32x4 o = O[qs][dt];                                                     \
        o = __builtin_amdgcn_mfma_f32_16x16x32_bf16(VFR[dt][0], PF[qs][0].v, o, 0,0,0); \
        o = __builtin_amdgcn_mfma_f32_16x16x32_bf16(VFR[dt][1], PF[qs][1].v, o, 0,0,0); \
        O[qs][dt] = o;                                                           \
      }                                                                          \
    __builtin_amdgcn_s_setprio(0);                                               \
  } while(0)

#define COMPUTE(KS, VS, FIRST)                                                   \
  do {                                                                           \
    if (!dg){                                                                    \
      pfu pfN[2][2]; bf16x8 vfrN[4][2];                                          \
      QK_EXP(KS, pfN);                                                           \
      LOADV(vfrN, VS);                                                           \
      PV(pfN, vfrN);                                                             \
    } else {                                                                     \
      if (!(FIRST)) PV(pfC, vfrC);                                               \
      QK_EXP(KS, pfC);                                                           \
      LOADV(vfrC, VS);                                                           \
    }                                                                            \
  } while(0)

  pfu pfC[2][2];
  bf16x8 vfrC[4][2];

  STAGE(Ks0, Vs0, 0);
  __syncthreads();
  STAGE(Ks1, Vs1, 1);
  COMPUTE(Ks0, Vs0, 1);
  __syncthreads();

  for (int kt = 1; kt < 63; kt += 2){
    STAGE(Ks0, Vs0, kt+1);
    COMPUTE(Ks1, Vs1, 0);
    __syncthreads();
    STAGE(Ks1, Vs1, kt+2);
    COMPUTE(Ks0, Vs0, 0);
    __syncthreads();
  }
  COMPUTE(Ks1, Vs1, 0);
  if (dg) PV(pfC, vfrC);

#undef STAGE
#undef QK_EXP
#undef LOADV
#undef PV
#undef COMPUTE

  #pragma unroll
  for (int qs=0; qs<2; ++qs){
    float l = lsum[qs];
    l += __shfl_xor(l, 16, 64);
    l += __shfl_xor(l, 32, 64);
    float inv = 1.0f / l;
    int query = q0 + qs*16 + l15;
    #pragma unroll
    for (int dt=0; dt<4; ++dt){
      float4 v;
      v.x = O[qs][dt][0]*inv; v.y = O[qs][dt][1]*inv;
      v.z = O[qs][dt][2]*inv; v.w = O[qs][dt][3]*inv;
      *(float4*)(out + (size_t)query*DIM + h*HD + dt*16 + quad*4) = v;
    }
  }
}

extern "C" void kernel_launch(void* const* d_in, const int* in_sizes, int n_in,
                              void* d_out, int out_size, void* d_ws, size_t ws_size,
                              hipStream_t stream)
{
  const float* X  = (const float*)d_in[0];
  const float* Wq = (const float*)d_in[1];
  const float* bq = (const float*)d_in[2];
  const float* Wk = (const float*)d_in[3];
  const float* bk = (const float*)d_in[4];
  const float* Wv = (const float*)d_in[5];
  const float* bv = (const float*)d_in[6];
  float* out = (float*)d_out;
  u16*   ws  = (u16*)d_ws;

  const size_t SD = (size_t)S_LEN * DIM;
  const size_t need_fast = (4*SD + 3*(size_t)DIM*DIM) * sizeof(u16);  // ~38 MB
  const size_t need_min  = (size_t)24 * 1024 * 1024;

  if (ws_size >= need_fast){
    u16* xbf = ws;
    u16* wt  = xbf + SD;
    u16* qb  = wt + 3*(size_t)DIM*DIM;
    u16* kf  = qb + SD;
    u16* vf  = kf + SD;
    prep_fused   <<<dim3(2048 + 768), 256, 0, stream>>>(X, xbf, Wq, Wk, Wv, wt);
    qkv_gemm_fast<<<dim3(768), 256, 0, stream>>>(xbf, wt, bq, bk, bv, qb, kf, vf);
    attn         <<<dim3(512), 256, 0, stream>>>(qb, kf, vf, out);
  } else if (ws_size >= need_min){
    u16* qb = ws;
    u16* kf = qb + SD;
    u16* vf = kf + SD;
    qkv_gemm_legacy<<<dim3(32, 8, 3), 256, 0, stream>>>(X, Wq, Wk, Wv, bq, bk, bv, qb, kf, vf);
    attn           <<<dim3(512), 256, 0, stream>>>(qb, kf, vf, out);
  } else {
    fill_sentinel<<<(out_size + 255)/256, 256, 0, stream>>>(out, out_size);
  }
}